// Round 2
// baseline (200.153 us; speedup 1.0000x reference)
//
#include <hip/hip_runtime.h>

typedef __attribute__((ext_vector_type(8))) short s8v;   // 8 bf16
typedef __attribute__((ext_vector_type(4))) short s4v;   // 4 bf16
typedef __attribute__((ext_vector_type(4))) float f4v;   // MFMA C/D

#define S_ 4096
#define E_ 1024
#define D_ 128

__device__ __forceinline__ unsigned short f2bf(float f) {
  unsigned int u = __float_as_uint(f);
  return (unsigned short)((u + 0x7FFFu + ((u >> 16) & 1u)) >> 16);
}

// async global->LDS, 16B per lane; LDS dest = wave-uniform base + lane*16
__device__ __forceinline__ void gload16(const void* g, void* l) {
  __builtin_amdgcn_global_load_lds(
      (const __attribute__((address_space(1))) unsigned int*)g,
      (__attribute__((address_space(3))) unsigned int*)l, 16, 0, 0);
}

// ---- zero the accumulators -------------------------------------------------
__global__ __launch_bounds__(256) void zero_kernel(float* __restrict__ p) {
  const int i = blockIdx.x * 256 + threadIdx.x;
  float4 z = {0.f, 0.f, 0.f, 0.f};
  reinterpret_cast<float4*>(p)[i] = z;
}

// ---- x cvt: x[16384][1024] f32 -> Xb bf16 (row-major, plain) ---------------
__global__ __launch_bounds__(256) void xcvt_kernel(
    const float* __restrict__ x, unsigned short* __restrict__ Xb) {
  const size_t i = ((size_t)blockIdx.x * 256 + threadIdx.x) * 8;
  float4 a = *reinterpret_cast<const float4*>(x + i);
  float4 b = *reinterpret_cast<const float4*>(x + i + 4);
  s8v v;
  v[0] = (short)f2bf(a.x); v[1] = (short)f2bf(a.y);
  v[2] = (short)f2bf(a.z); v[3] = (short)f2bf(a.w);
  v[4] = (short)f2bf(b.x); v[5] = (short)f2bf(b.y);
  v[6] = (short)f2bf(b.z); v[7] = (short)f2bf(b.w);
  *reinterpret_cast<s8v*>(Xb + i) = v;
}

// ---- W cvt+transpose: W[p][k][n] f32 -> Wt[p*128+n][k] bf16 ----------------
__global__ __launch_bounds__(256) void wcvt_kernel(
    const float* __restrict__ Wq, const float* __restrict__ Wk,
    const float* __restrict__ Wv, unsigned short* __restrict__ Wt) {
  __shared__ unsigned short T[64][72];
  const int p = blockIdx.y;
  const float* W = (p == 0) ? Wq : (p == 1) ? Wk : Wv;
  const int k0 = (blockIdx.x >> 1) * 64;
  const int n0 = (blockIdx.x & 1) * 64;
  const int t = threadIdx.x, rr = t >> 4, c4 = (t & 15) * 4;
#pragma unroll
  for (int i = 0; i < 4; ++i) {
    int kr = i * 16 + rr;
    float4 w = *reinterpret_cast<const float4*>(W + (size_t)(k0 + kr) * D_ + n0 + c4);
    T[c4 + 0][kr] = f2bf(w.x); T[c4 + 1][kr] = f2bf(w.y);
    T[c4 + 2][kr] = f2bf(w.z); T[c4 + 3][kr] = f2bf(w.w);
  }
  __syncthreads();
#pragma unroll
  for (int i = 0; i < 4; ++i) {
    int n = i * 16 + rr;
    s4v v;
    v[0] = (short)T[n][c4]; v[1] = (short)T[n][c4 + 1];
    v[2] = (short)T[n][c4 + 2]; v[3] = (short)T[n][c4 + 3];
    *reinterpret_cast<s4v*>(Wt + (size_t)(p * D_ + n0 + n) * E_ + k0 + c4) = v;
  }
}

// ---- fused QKV projection v2: m97 structure --------------------------------
// BM=BN=128, BK=64, 256 threads (4 waves, 64x64 wave-tiles, acc[4][4]).
// Staging via global_load_lds (16B/lane, 4 instr/wave/operand) into LINEAR
// LDS [128][64]bf16; per-lane GLOBAL source address pre-swizzled by
// ((l&7)^(l>>3))*16 bytes so that fragment ds_read_b128 at
// col^( (row&7)*16 ) is bank-conflict-free (m201 both-sides swizzle).
// grid 384: cls=bid&7 -> XCD; 3 consecutive j share an m-tile (Xb L2-hit).
__global__ __launch_bounds__(256) void proj_kernel(
    const unsigned short* __restrict__ Xb, const unsigned short* __restrict__ Wt,
    unsigned short* __restrict__ Qb, unsigned short* __restrict__ Kb,
    unsigned short* __restrict__ VT) {
  __shared__ __align__(16) unsigned short As[128 * 64];
  __shared__ __align__(16) unsigned short Bs[128 * 64];
  const int bid = blockIdx.x;
  const int cls = bid & 7, j = bid >> 3;
  const int m0 = (cls * 16 + j / 3) * 128, ng = j % 3;
  const int t = threadIdx.x;
  const int wv = t >> 6, lane = t & 63, quad = lane >> 4, l16 = lane & 15;
  const int wr = wv >> 1, wc = wv & 1;  // wave-tile 64x64

  f4v acc[4][4];
  const f4v fz = {0.f, 0.f, 0.f, 0.f};
#pragma unroll
  for (int i = 0; i < 4; ++i)
#pragma unroll
    for (int k = 0; k < 4; ++k) acc[i][k] = fz;

  // staging: instr i of wave wv covers tile rows wv*32+i*8 .. +7
  const int rbase = wv * 32 + (lane >> 3);
  const int scb = ((lane & 7) ^ (lane >> 3)) * 16;  // pre-swizzled byte col
  const char* aSrc = (const char*)(Xb + (size_t)(m0 + rbase) * E_) + scb;
  const char* bSrc = (const char*)(Wt + (size_t)(ng * 128 + rbase) * E_) + scb;
  char* aDst = (char*)As + wv * 4096;
  char* bDst = (char*)Bs + wv * 4096;

  const int xm = (l16 & 7) * 16;  // read-side swizzle mask
  const char* Ab = (const char*)As + (wr * 64 + l16) * 128;
  const char* Bb = (const char*)Bs + (wc * 64 + l16) * 128;

  for (int kk = 0; kk < E_; kk += 64) {
#pragma unroll
    for (int i = 0; i < 4; ++i)
      gload16(aSrc + (size_t)i * (8 * E_ * 2) + kk * 2, aDst + i * 1024);
#pragma unroll
    for (int i = 0; i < 4; ++i)
      gload16(bSrc + (size_t)i * (8 * E_ * 2) + kk * 2, bDst + i * 1024);
    __syncthreads();  // drains vmcnt then barrier: LDS tile complete
#pragma unroll
    for (int ks = 0; ks < 2; ++ks) {
      const int co = (ks * 64 + quad * 16) ^ xm;
      s8v af[4], bf[4];
#pragma unroll
      for (int rt = 0; rt < 4; ++rt)
        af[rt] = *reinterpret_cast<const s8v*>(Ab + rt * 16 * 128 + co);
#pragma unroll
      for (int ct = 0; ct < 4; ++ct)
        bf[ct] = *reinterpret_cast<const s8v*>(Bb + ct * 16 * 128 + co);
#pragma unroll
      for (int rt = 0; rt < 4; ++rt)
#pragma unroll
        for (int ct = 0; ct < 4; ++ct)
          acc[rt][ct] = __builtin_amdgcn_mfma_f32_16x16x32_bf16(
              af[rt], bf[ct], acc[rt][ct], 0, 0, 0);
    }
    __syncthreads();  // before overwriting LDS next iter
  }

  if (ng < 2) {
    unsigned short* dst = ng ? Kb : Qb;
#pragma unroll
    for (int rt = 0; rt < 4; ++rt)
#pragma unroll
      for (int ct = 0; ct < 4; ++ct)
#pragma unroll
        for (int r = 0; r < 4; ++r)
          dst[(size_t)(m0 + wr * 64 + rt * 16 + quad * 4 + r) * D_ +
              wc * 64 + ct * 16 + l16] = f2bf(acc[rt][ct][r]);
  } else {
    const int b = m0 >> 12;
    const int s0 = (m0 & (S_ - 1)) + wr * 64;
#pragma unroll
    for (int rt = 0; rt < 4; ++rt)
#pragma unroll
      for (int ct = 0; ct < 4; ++ct) {
        s4v v;
        v[0] = (short)f2bf(acc[rt][ct][0]); v[1] = (short)f2bf(acc[rt][ct][1]);
        v[2] = (short)f2bf(acc[rt][ct][2]); v[3] = (short)f2bf(acc[rt][ct][3]);
        *reinterpret_cast<s4v*>(
            VT + ((size_t)b * D_ + wc * 64 + ct * 16 + l16) * S_ + s0 +
            rt * 16 + quad * 4) = v;
      }
  }
}

// ---- flash: 64-q blocks (16 q/wave), 512-key chunks, XOR-16 KS swizzle -----
// grid 1152: xcd = id&7 -> (batch, half-class); sub = heavy-first (qt, s)
// triangular decode over 64-row q-tiles. Block = 64 q-rows x one 512-key
// chunk (<=8 64-key iters); 16 q-rows/wave so VGPR stays low:
// 4 waves/SIMD x 4 blocks/CU (LDS 34KB) resident.
__global__ __launch_bounds__(256, 4) void flash_kernel(
    const unsigned short* __restrict__ Qb, const unsigned short* __restrict__ Kb,
    const unsigned short* __restrict__ VT, float* __restrict__ Oacc,
    float* __restrict__ Lacc) {
  __shared__ __align__(16) unsigned short KS[64 * 128];
  __shared__ __align__(16) unsigned short VS[128 * 72];
  const int id = blockIdx.x;
  const int xcd = id & 7;
  const int b = xcd >> 1;
  const int sub = 287 - ((id >> 3) * 2 + (xcd & 1));  // heavy-first
  int g = 0;
#pragma unroll
  for (int gg = 0; gg < 7; ++gg)
    if (sub >= 4 * (gg + 1) * (gg + 2)) g = gg + 1;
  const int off = sub - 4 * g * (g + 1);
  const int qt = 8 * g + off / (g + 1);
  const int s = off % (g + 1);
  const int q0 = qt * 64;
  const int klo = s * 512;
  const int khi = min((s + 1) * 512, (qt + 1) * 64);

  const int t = threadIdx.x;
  const int wv = t >> 6, lane = t & 63, quad = lane >> 4, l16 = lane & 15;
  const int qrow0 = q0 + wv * 16;
  const float SCL2 = 0.03125f * 1.44269504088896340736f;  // (1/32)*log2(e)

  const unsigned short* Kbb = Kb + (size_t)b * S_ * D_;
  const unsigned short* Vbb = VT + (size_t)b * D_ * S_;

  s8v Qf[4];
#pragma unroll
  for (int ks = 0; ks < 4; ++ks)
    Qf[ks] = *reinterpret_cast<const s8v*>(
        Qb + ((size_t)b * S_ + qrow0 + l16) * D_ + ks * 32 + quad * 8);

  f4v O[8];
  const f4v fz = {0.f, 0.f, 0.f, 0.f};
#pragma unroll
  for (int nt = 0; nt < 8; ++nt) O[nt] = fz;
  float lt = 0.f;

  // staging: K rows krow+16i (granule kgb); V d-rows vrow (granules vgb+i)
  const int krow = t >> 4, kgb = t & 15;
  const int vrow = t >> 1, vgb = (t & 1) * 4;

  s8v kr[4], vr[4];
#pragma unroll
  for (int i = 0; i < 4; ++i) {
    kr[i] = *reinterpret_cast<const s8v*>(
        Kbb + (size_t)(klo + krow + 16 * i) * D_ + kgb * 8);
    vr[i] = *reinterpret_cast<const s8v*>(
        Vbb + (size_t)vrow * S_ + klo + (vgb + i) * 8);
  }

  for (int k0 = klo; k0 < khi; k0 += 64) {
    __syncthreads();
#pragma unroll
    for (int i = 0; i < 4; ++i) {
      const int r = krow + 16 * i;
      const int sig = (krow & 3) | ((((krow >> 3) + 2 * i) & 3) << 2);
      *reinterpret_cast<s8v*>(KS + r * 128 + ((kgb ^ sig) * 8)) = kr[i];
      *reinterpret_cast<s8v*>(VS + vrow * 72 + (vgb + i) * 8) = vr[i];
    }
    __syncthreads();
    if (k0 + 64 < khi) {  // issue next-tile loads; in flight during compute
#pragma unroll
      for (int i = 0; i < 4; ++i) {
        kr[i] = *reinterpret_cast<const s8v*>(
            Kbb + (size_t)(k0 + 64 + krow + 16 * i) * D_ + kgb * 8);
        vr[i] = *reinterpret_cast<const s8v*>(
            Vbb + (size_t)vrow * S_ + k0 + 64 + (vgb + i) * 8);
      }
    }

    if (k0 <= qrow0 + 15) {  // wave-uniform causal skip
      f4v St[2][2];  // [chunk c][s2]
#pragma unroll
      for (int c = 0; c < 2; ++c)
#pragma unroll
        for (int s2 = 0; s2 < 2; ++s2) St[c][s2] = fz;
#pragma unroll
      for (int ks = 0; ks < 4; ++ks)
#pragma unroll
        for (int c = 0; c < 2; ++c)
#pragma unroll
          for (int s2 = 0; s2 < 2; ++s2) {
            const int row = c * 32 + ((l16 >> 2) << 3) + s2 * 4 + (l16 & 3);
            s8v kf = *reinterpret_cast<const s8v*>(
                KS + row * 128 + (((ks * 4 + quad) ^ l16) * 8));
            St[c][s2] = __builtin_amdgcn_mfma_f32_16x16x32_bf16(
                kf, Qf[ks], St[c][s2], 0, 0, 0);
          }
      const bool full = (k0 + 63 <= qrow0);
      s8v pf[2];  // [c]
#pragma unroll
      for (int c = 0; c < 2; ++c) {
        float ladd = 0.f;
#pragma unroll
        for (int s2 = 0; s2 < 2; ++s2)
#pragma unroll
          for (int r = 0; r < 4; ++r) {
            float e = exp2f(St[c][s2][r] * SCL2);
            if (!full) {
              int key = k0 + c * 32 + quad * 8 + s2 * 4 + r;
              if (key > qrow0 + l16) e = 0.f;
            }
            ladd += e;
            pf[c][s2 * 4 + r] = (short)f2bf(e);
          }
        lt += ladd;
      }
#pragma unroll
      for (int c = 0; c < 2; ++c)
#pragma unroll
        for (int nt = 0; nt < 8; ++nt) {
          s8v vf = *reinterpret_cast<const s8v*>(
              VS + (nt * 16 + l16) * 72 + (c * 4 + quad) * 8);
          O[nt] = __builtin_amdgcn_mfma_f32_16x16x32_bf16(
              pf[c], vf, O[nt], 0, 0, 0);
        }
    }
  }

  // epilogue: atomically accumulate partial (O, l)
  lt += __shfl_xor(lt, 16);
  lt += __shfl_xor(lt, 32);
  float* Ob = Oacc + (size_t)b * S_ * D_;
#pragma unroll
  for (int nt = 0; nt < 8; ++nt)
#pragma unroll
    for (int r = 0; r < 4; ++r)
      atomicAdd(&Ob[(size_t)(qrow0 + quad * 4 + r) * D_ + nt * 16 + l16],
                O[nt][r]);
  if (lane < 16) atomicAdd(&Lacc[(size_t)b * S_ + qrow0 + l16], lt);
}

// ---- normalize: out = Oacc / Lacc ------------------------------------------
__global__ __launch_bounds__(256) void norm_kernel(
    const float* __restrict__ Oacc, const float* __restrict__ Lacc,
    float* __restrict__ out) {
  const int idx = blockIdx.x * 256 + threadIdx.x;
  const int base = idx * 4;
  const int row = base >> 7;
  float4 o = reinterpret_cast<const float4*>(Oacc)[idx];
  float L = Lacc[row];
  float4 r;
  r.x = o.x / L; r.y = o.y / L; r.z = o.z / L; r.w = o.w / L;
  reinterpret_cast<float4*>(out)[idx] = r;
}

extern "C" void kernel_launch(void* const* d_in, const int* in_sizes, int n_in,
                              void* d_out, int out_size, void* d_ws, size_t ws_size,
                              hipStream_t stream) {
  const float* x = (const float*)d_in[0];
  const float* Wq = (const float*)d_in[1];
  const float* Wk = (const float*)d_in[2];
  const float* Wv = (const float*)d_in[3];
  float* out = (float*)d_out;

  char* ws = (char*)d_ws;
  unsigned short* Qb = (unsigned short*)ws;                           // 4 MB
  unsigned short* Kb = (unsigned short*)(ws + (((size_t)4) << 20));   // 4 MB
  unsigned short* VT = (unsigned short*)(ws + (((size_t)8) << 20));   // 4 MB
  unsigned short* Wt = (unsigned short*)(ws + (((size_t)12) << 20));  // 0.75 MB
  // Xb (32 MB) aliases Oacc/Lacc: Xb is consumed by proj BEFORE zero_kernel
  // initializes Oacc/Lacc (stream-ordered). Total workspace: 45 MB.
  unsigned short* Xb = (unsigned short*)(ws + (((size_t)13) << 20));  // 32 MB
  float* Oacc = (float*)(ws + (((size_t)13) << 20));                  // 8 MB
  float* Lacc = (float*)(ws + (((size_t)21) << 20));                  // 64 KB

  wcvt_kernel<<<dim3(32, 3), 256, 0, stream>>>(Wq, Wk, Wv, Wt);
  xcvt_kernel<<<8192, 256, 0, stream>>>(x, Xb);
  proj_kernel<<<384, 256, 0, stream>>>(Xb, Wt, Qb, Kb, VT);
  zero_kernel<<<2064, 256, 0, stream>>>(Oacc);  // covers Oacc+Lacc contiguous
  flash_kernel<<<1152, 256, 0, stream>>>(Qb, Kb, VT, Oacc, Lacc);
  norm_kernel<<<2048, 256, 0, stream>>>(Oacc, Lacc, out);
}

// Round 3
// 167.813 us; speedup vs baseline: 1.1927x; 1.1927x over previous
//
#include <hip/hip_runtime.h>

typedef __attribute__((ext_vector_type(8))) short s8v;   // 8 bf16
typedef __attribute__((ext_vector_type(4))) short s4v;   // 4 bf16
typedef __attribute__((ext_vector_type(4))) float f4v;   // MFMA C/D

#define S_ 4096
#define E_ 1024
#define D_ 128

__device__ __forceinline__ unsigned short f2bf(float f) {
  unsigned int u = __float_as_uint(f);
  return (unsigned short)((u + 0x7FFFu + ((u >> 16) & 1u)) >> 16);
}

// async global->LDS, 16B per lane; LDS dest = wave-uniform base + lane*16
__device__ __forceinline__ void gload16(const void* g, void* l) {
  __builtin_amdgcn_global_load_lds(
      (const __attribute__((address_space(1))) unsigned int*)g,
      (__attribute__((address_space(3))) unsigned int*)l, 16, 0, 0);
}

// packed partial-slot row offset: slot s covers q-rows [512s, 4096)
__device__ __forceinline__ int slot_off(int s) { return s * (3840 - 256 * s); }

// ---- prep: xcvt (blocks 0..8191) + wcvt (blocks 8192..8287) ---------------
__global__ __launch_bounds__(256) void prep_kernel(
    const float* __restrict__ x, const float* __restrict__ Wq,
    const float* __restrict__ Wk, const float* __restrict__ Wv,
    unsigned short* __restrict__ Xb, unsigned short* __restrict__ Wt) {
  __shared__ unsigned short T[64][72];
  const int bid = blockIdx.x;
  if (bid < 8192) {  // x f32 -> bf16
    const size_t i = ((size_t)bid * 256 + threadIdx.x) * 8;
    float4 a = *reinterpret_cast<const float4*>(x + i);
    float4 c = *reinterpret_cast<const float4*>(x + i + 4);
    s8v v;
    v[0] = (short)f2bf(a.x); v[1] = (short)f2bf(a.y);
    v[2] = (short)f2bf(a.z); v[3] = (short)f2bf(a.w);
    v[4] = (short)f2bf(c.x); v[5] = (short)f2bf(c.y);
    v[6] = (short)f2bf(c.z); v[7] = (short)f2bf(c.w);
    *reinterpret_cast<s8v*>(Xb + i) = v;
  } else {  // W cvt+transpose: W[p][k][n] f32 -> Wt[p*128+n][k] bf16
    const int w = bid - 8192;
    const int p = w >> 5, bx = w & 31;
    const float* W = (p == 0) ? Wq : (p == 1) ? Wk : Wv;
    const int k0 = (bx >> 1) * 64;
    const int n0 = (bx & 1) * 64;
    const int t = threadIdx.x, rr = t >> 4, c4 = (t & 15) * 4;
#pragma unroll
    for (int i = 0; i < 4; ++i) {
      int kr = i * 16 + rr;
      float4 ww = *reinterpret_cast<const float4*>(W + (size_t)(k0 + kr) * D_ + n0 + c4);
      T[c4 + 0][kr] = f2bf(ww.x); T[c4 + 1][kr] = f2bf(ww.y);
      T[c4 + 2][kr] = f2bf(ww.z); T[c4 + 3][kr] = f2bf(ww.w);
    }
    __syncthreads();
#pragma unroll
    for (int i = 0; i < 4; ++i) {
      int n = i * 16 + rr;
      s4v v;
      v[0] = (short)T[n][c4]; v[1] = (short)T[n][c4 + 1];
      v[2] = (short)T[n][c4 + 2]; v[3] = (short)T[n][c4 + 3];
      *reinterpret_cast<s4v*>(Wt + (size_t)(p * D_ + n0 + n) * E_ + k0 + c4) = v;
    }
  }
}

// ---- fused QKV projection v3: BM=128, BN=64, BK=64, grid 768 (3 blk/CU) ----
// 4 waves as 2x2, wave-tile 64x32, acc[4][2]. Staging via global_load_lds
// (16B/lane) into LINEAR LDS; per-lane GLOBAL source pre-swizzled by
// ((l&7)^(l>>3))*16 so fragment ds_read_b128 at col^((row&7)*16) is
// bank-conflict-free (m201 both-sides swizzle). cls=bid&7 -> XCD; the 6
// n-groups of one m-tile are consecutive j on one XCD (Xb tile L2-hit).
__global__ __launch_bounds__(256, 3) void proj_kernel(
    const unsigned short* __restrict__ Xb, const unsigned short* __restrict__ Wt,
    unsigned short* __restrict__ Qb, unsigned short* __restrict__ Kb,
    unsigned short* __restrict__ VT) {
  __shared__ __align__(16) unsigned short As[128 * 64];
  __shared__ __align__(16) unsigned short Bs[64 * 64];
  const int bid = blockIdx.x;
  const int cls = bid & 7, j = bid >> 3;            // j 0..95
  const int m0 = (cls * 16 + j / 6) * 128, ng = j % 6;
  const int t = threadIdx.x;
  const int wv = t >> 6, lane = t & 63, quad = lane >> 4, l16 = lane & 15;
  const int wr = wv >> 1, wc = wv & 1;  // wave-tile 64x32

  f4v acc[4][2];
  const f4v fz = {0.f, 0.f, 0.f, 0.f};
#pragma unroll
  for (int i = 0; i < 4; ++i)
#pragma unroll
    for (int k = 0; k < 2; ++k) acc[i][k] = fz;

  const int lrow = lane >> 3;
  const int scb = ((lane & 7) ^ lrow) * 16;  // pre-swizzled byte col
  const char* aSrc = (const char*)(Xb + (size_t)(m0 + wv * 32 + lrow) * E_) + scb;
  const char* bSrc = (const char*)(Wt + (size_t)(ng * 64 + wv * 16 + lrow) * E_) + scb;
  char* aDst = (char*)As + wv * 4096;
  char* bDst = (char*)Bs + wv * 2048;

  const int xm = (l16 & 7) * 16;  // read-side swizzle mask
  const char* Ab = (const char*)As + (wr * 64 + l16) * 128;
  const char* Bb = (const char*)Bs + (wc * 32 + l16) * 128;

  for (int kk = 0; kk < E_; kk += 64) {
#pragma unroll
    for (int i = 0; i < 4; ++i)
      gload16(aSrc + (size_t)(i * 8 * E_ + kk) * 2, aDst + i * 1024);
#pragma unroll
    for (int i = 0; i < 2; ++i)
      gload16(bSrc + (size_t)(i * 8 * E_ + kk) * 2, bDst + i * 1024);
    __syncthreads();  // drains vmcnt then barrier: LDS tile complete
#pragma unroll
    for (int ks = 0; ks < 2; ++ks) {
      const int co = (ks * 64 + quad * 16) ^ xm;
      s8v af[4], bf[2];
#pragma unroll
      for (int rt = 0; rt < 4; ++rt)
        af[rt] = *reinterpret_cast<const s8v*>(Ab + rt * 2048 + co);
#pragma unroll
      for (int ct = 0; ct < 2; ++ct)
        bf[ct] = *reinterpret_cast<const s8v*>(Bb + ct * 2048 + co);
#pragma unroll
      for (int rt = 0; rt < 4; ++rt)
#pragma unroll
        for (int ct = 0; ct < 2; ++ct)
          acc[rt][ct] = __builtin_amdgcn_mfma_f32_16x16x32_bf16(
              af[rt], bf[ct], acc[rt][ct], 0, 0, 0);
    }
    __syncthreads();  // before overwriting LDS next iter
  }

  const int p = ng >> 1, n0 = (ng & 1) * 64;
  if (p < 2) {
    unsigned short* dst = p ? Kb : Qb;
#pragma unroll
    for (int rt = 0; rt < 4; ++rt)
#pragma unroll
      for (int ct = 0; ct < 2; ++ct)
#pragma unroll
        for (int r = 0; r < 4; ++r)
          dst[(size_t)(m0 + wr * 64 + rt * 16 + quad * 4 + r) * D_ +
              n0 + wc * 32 + ct * 16 + l16] = f2bf(acc[rt][ct][r]);
  } else {
    const int b = m0 >> 12;
    const int s0 = (m0 & (S_ - 1)) + wr * 64;
#pragma unroll
    for (int rt = 0; rt < 4; ++rt)
#pragma unroll
      for (int ct = 0; ct < 2; ++ct) {
        s4v v;
        v[0] = (short)f2bf(acc[rt][ct][0]); v[1] = (short)f2bf(acc[rt][ct][1]);
        v[2] = (short)f2bf(acc[rt][ct][2]); v[3] = (short)f2bf(acc[rt][ct][3]);
        *reinterpret_cast<s4v*>(
            VT + ((size_t)b * D_ + n0 + wc * 32 + ct * 16 + l16) * S_ + s0 +
            rt * 16 + quad * 4) = v;
      }
  }
}

// ---- flash: 64-q blocks (16 q/wave), 512-key chunks, XOR-16 KS swizzle -----
// grid 1152: xcd = id&7 -> (batch, half-class); sub = heavy-first (qt, s)
// triangular decode over 64-row q-tiles. Partials go to DISJOINT packed
// slots (no atomics, no zero-init): Op[(row + slot_off(s))*4 + b][d].
__global__ __launch_bounds__(256, 4) void flash_kernel(
    const unsigned short* __restrict__ Qb, const unsigned short* __restrict__ Kb,
    const unsigned short* __restrict__ VT, float* __restrict__ Op,
    float* __restrict__ Lp) {
  __shared__ __align__(16) unsigned short KS[64 * 128];
  __shared__ __align__(16) unsigned short VS[128 * 72];
  const int id = blockIdx.x;
  const int xcd = id & 7;
  const int b = xcd >> 1;
  const int sub = 287 - ((id >> 3) * 2 + (xcd & 1));  // heavy-first
  int g = 0;
#pragma unroll
  for (int gg = 0; gg < 7; ++gg)
    if (sub >= 4 * (gg + 1) * (gg + 2)) g = gg + 1;
  const int off = sub - 4 * g * (g + 1);
  const int qt = 8 * g + off / (g + 1);
  const int s = off % (g + 1);
  const int q0 = qt * 64;
  const int klo = s * 512;
  const int khi = min((s + 1) * 512, (qt + 1) * 64);

  const int t = threadIdx.x;
  const int wv = t >> 6, lane = t & 63, quad = lane >> 4, l16 = lane & 15;
  const int qrow0 = q0 + wv * 16;
  const float SCL2 = 0.03125f * 1.44269504088896340736f;  // (1/32)*log2(e)

  const unsigned short* Kbb = Kb + (size_t)b * S_ * D_;
  const unsigned short* Vbb = VT + (size_t)b * D_ * S_;

  s8v Qf[4];
#pragma unroll
  for (int ks = 0; ks < 4; ++ks)
    Qf[ks] = *reinterpret_cast<const s8v*>(
        Qb + ((size_t)b * S_ + qrow0 + l16) * D_ + ks * 32 + quad * 8);

  f4v O[8];
  const f4v fz = {0.f, 0.f, 0.f, 0.f};
#pragma unroll
  for (int nt = 0; nt < 8; ++nt) O[nt] = fz;
  float lt = 0.f;

  // staging: K rows krow+16i (granule kgb); V d-rows vrow (granules vgb+i)
  const int krow = t >> 4, kgb = t & 15;
  const int vrow = t >> 1, vgb = (t & 1) * 4;

  s8v kr[4], vr[4];
#pragma unroll
  for (int i = 0; i < 4; ++i) {
    kr[i] = *reinterpret_cast<const s8v*>(
        Kbb + (size_t)(klo + krow + 16 * i) * D_ + kgb * 8);
    vr[i] = *reinterpret_cast<const s8v*>(
        Vbb + (size_t)vrow * S_ + klo + (vgb + i) * 8);
  }

  for (int k0 = klo; k0 < khi; k0 += 64) {
    __syncthreads();
#pragma unroll
    for (int i = 0; i < 4; ++i) {
      const int r = krow + 16 * i;
      const int sig = (krow & 3) | ((((krow >> 3) + 2 * i) & 3) << 2);
      *reinterpret_cast<s8v*>(KS + r * 128 + ((kgb ^ sig) * 8)) = kr[i];
      *reinterpret_cast<s8v*>(VS + vrow * 72 + (vgb + i) * 8) = vr[i];
    }
    __syncthreads();
    if (k0 + 64 < khi) {  // issue next-tile loads; in flight during compute
#pragma unroll
      for (int i = 0; i < 4; ++i) {
        kr[i] = *reinterpret_cast<const s8v*>(
            Kbb + (size_t)(k0 + 64 + krow + 16 * i) * D_ + kgb * 8);
        vr[i] = *reinterpret_cast<const s8v*>(
            Vbb + (size_t)vrow * S_ + k0 + 64 + (vgb + i) * 8);
      }
    }

    if (k0 <= qrow0 + 15) {  // wave-uniform causal skip
      f4v St[2][2];  // [chunk c][s2]
#pragma unroll
      for (int c = 0; c < 2; ++c)
#pragma unroll
        for (int s2 = 0; s2 < 2; ++s2) St[c][s2] = fz;
      __builtin_amdgcn_s_setprio(1);
#pragma unroll
      for (int ks = 0; ks < 4; ++ks)
#pragma unroll
        for (int c = 0; c < 2; ++c)
#pragma unroll
          for (int s2 = 0; s2 < 2; ++s2) {
            const int row = c * 32 + ((l16 >> 2) << 3) + s2 * 4 + (l16 & 3);
            s8v kf = *reinterpret_cast<const s8v*>(
                KS + row * 128 + (((ks * 4 + quad) ^ l16) * 8));
            St[c][s2] = __builtin_amdgcn_mfma_f32_16x16x32_bf16(
                kf, Qf[ks], St[c][s2], 0, 0, 0);
          }
      __builtin_amdgcn_s_setprio(0);
      const bool full = (k0 + 63 <= qrow0);
      s8v pf[2];  // [c]
#pragma unroll
      for (int c = 0; c < 2; ++c) {
        float ladd = 0.f;
#pragma unroll
        for (int s2 = 0; s2 < 2; ++s2)
#pragma unroll
          for (int r = 0; r < 4; ++r) {
            float e = exp2f(St[c][s2][r] * SCL2);
            if (!full) {
              int key = k0 + c * 32 + quad * 8 + s2 * 4 + r;
              if (key > qrow0 + l16) e = 0.f;
            }
            ladd += e;
            pf[c][s2 * 4 + r] = (short)f2bf(e);
          }
        lt += ladd;
      }
      __builtin_amdgcn_s_setprio(1);
#pragma unroll
      for (int c = 0; c < 2; ++c)
#pragma unroll
        for (int nt = 0; nt < 8; ++nt) {
          s8v vf = *reinterpret_cast<const s8v*>(
              VS + (nt * 16 + l16) * 72 + (c * 4 + quad) * 8);
          O[nt] = __builtin_amdgcn_mfma_f32_16x16x32_bf16(
              pf[c], vf, O[nt], 0, 0, 0);
        }
      __builtin_amdgcn_s_setprio(0);
    }
  }

  // epilogue: plain stores to this (qt,s)-chunk's private packed slot
  lt += __shfl_xor(lt, 16);
  lt += __shfl_xor(lt, 32);
  const int soff = slot_off(s);
#pragma unroll
  for (int nt = 0; nt < 8; ++nt)
#pragma unroll
    for (int r = 0; r < 4; ++r)
      Op[((size_t)(qrow0 + quad * 4 + r + soff) * 4 + b) * D_ + nt * 16 + l16] =
          O[nt][r];
  if (lane < 16) Lp[(size_t)(qrow0 + l16 + soff) * 4 + b] = lt;
}

// ---- normalize: out[b][row][:] = sum_s Op_s / sum_s Lp_s -------------------
__global__ __launch_bounds__(256) void norm_kernel(
    const float* __restrict__ Op, const float* __restrict__ Lp,
    float* __restrict__ out) {
  const int idx = blockIdx.x * 256 + threadIdx.x;  // float4 index
  const int rowg = idx >> 5, d4 = idx & 31;        // 32 float4 per row
  const int b = rowg >> 12, row = rowg & 4095;
  const int g = row >> 9;  // chunks-1 for this row
  float ax = 0.f, ay = 0.f, az = 0.f, aw = 0.f, L = 0.f;
  for (int s = 0; s <= g; ++s) {
    const size_t pr = (size_t)(row + slot_off(s)) * 4 + b;
    float4 o = reinterpret_cast<const float4*>(Op + pr * D_)[d4];
    ax += o.x; ay += o.y; az += o.z; aw += o.w;
    L += Lp[pr];
  }
  float4 r;
  const float inv = 1.f / L;
  r.x = ax * inv; r.y = ay * inv; r.z = az * inv; r.w = aw * inv;
  reinterpret_cast<float4*>(out)[idx] = r;
}

extern "C" void kernel_launch(void* const* d_in, const int* in_sizes, int n_in,
                              void* d_out, int out_size, void* d_ws, size_t ws_size,
                              hipStream_t stream) {
  const float* x = (const float*)d_in[0];
  const float* Wq = (const float*)d_in[1];
  const float* Wk = (const float*)d_in[2];
  const float* Wv = (const float*)d_in[3];
  float* out = (float*)d_out;

  char* ws = (char*)d_ws;
  unsigned short* Qb = (unsigned short*)ws;                           // 4 MB
  unsigned short* Kb = (unsigned short*)(ws + (((size_t)4) << 20));   // 4 MB
  unsigned short* VT = (unsigned short*)(ws + (((size_t)8) << 20));   // 4 MB
  unsigned short* Wt = (unsigned short*)(ws + (((size_t)12) << 20));  // 0.75 MB
  // Xb (32 MB) aliases Op (36 MB): Xb is consumed by proj BEFORE flash
  // writes Op (stream-ordered). Total workspace: ~50.5 MB.
  unsigned short* Xb = (unsigned short*)(ws + (((size_t)13) << 20));  // 32 MB
  float* Op = (float*)(ws + (((size_t)13) << 20));                    // 36 MB
  float* Lp = (float*)(ws + (((size_t)50) << 20));                    // 0.3 MB

  prep_kernel<<<8288, 256, 0, stream>>>(x, Wq, Wk, Wv, Xb, Wt);
  proj_kernel<<<768, 256, 0, stream>>>(Xb, Wt, Qb, Kb, VT);
  flash_kernel<<<1152, 256, 0, stream>>>(Qb, Kb, VT, Op, Lp);
  norm_kernel<<<2048, 256, 0, stream>>>(Op, Lp, out);
}